// Round 8
// baseline (283.052 us; speedup 1.0000x reference)
//
#include <hip/hip_runtime.h>

// ---- problem constants ----
#define TT 100
#define BB 1024
#define NI 256
#define NH 512
#define NO 10
#define TB (TT*BB)            // 102400 rows
#define GK 512                 // doubled K (hi/lo interleave)
#define GN 512

// output layout (floats), return order: cur1, cur2, spk1, spk2, mem1, mem2
constexpr long long C1_OFF = 0;
constexpr long long C2_OFF = 52428800LL;            // + T*B*NH
constexpr long long S1_OFF = 53452800LL;            // + T*B*NO
constexpr long long S2_OFF = 105881600LL;
constexpr long long M1_OFF = 106905600LL;
constexpr long long M2_OFF = 159334400LL;

typedef short bf16x8 __attribute__((ext_vector_type(8)));
typedef float f32x4 __attribute__((ext_vector_type(4)));

// round-to-nearest-even f32 -> bf16 bits
__device__ __forceinline__ unsigned int rne_bf16(float f) {
    unsigned int u = __float_as_uint(f);
    return (u + 0x7fffu + ((u >> 16) & 1u)) >> 16;
}

// f32 -> packed [hi,lo] bf16 pair (Dekker split), bit-identical to prior rounds
__device__ __forceinline__ unsigned int pack_hilo(float f) {
    unsigned int hi = rne_bf16(f);
    float hif = __uint_as_float(hi << 16);
    float e = f - hif;
    unsigned int lo = rne_bf16(e);
    return (hi & 0xffffu) | (lo << 16);
}

__device__ __forceinline__ void pack4(uint4& d, const float4& a) {
    d.x = pack_hilo(a.x); d.y = pack_hilo(a.y); d.z = pack_hilo(a.z); d.w = pack_hilo(a.w);
}

// async global->LDS, 16B per lane; LDS dest = wave-uniform base + lane*16
__device__ __forceinline__ void gload16(const void* g, void* l) {
    __builtin_amdgcn_global_load_lds(
        (const __attribute__((address_space(1))) void*)g,
        (__attribute__((address_space(3))) void*)l, 16, 0, 0);
}

// LDS-only barrier (R5-proven correct): orders ds traffic without draining the
// global store stream (__syncthreads would emit s_waitcnt vmcnt(0)).
__device__ __forceinline__ void barrier_lds() {
    asm volatile("s_waitcnt lgkmcnt(0)" ::: "memory");
    __builtin_amdgcn_s_barrier();
}

// Counted barrier for the gemm K-loop: drain this iter's 2 global_load_lds
// (W tile, L2-hot, latency covered by the iter body) but leave the 2 newest
// VMEM ops (this iter's x raw prefetches, HBM, consumed 2 iters later) in
// flight across the barrier. vmcnt retires in issue order (per-wave), so with
// the forced order [gload x2, raw x2] vmcnt(2) provably retires the gloads.
__device__ __forceinline__ void barrier_vm2() {
    asm volatile("s_waitcnt vmcnt(2) lgkmcnt(0)" ::: "memory");
    __builtin_amdgcn_s_barrier();
}

// ---- prep: W1 (f32 {0,0.5}) -> pre-swizzled LDS-image (R2-proven) ----
__global__ void prep_w_kernel(const float* __restrict__ W1, short* __restrict__ Wimg) {
    int i = blockIdx.x * blockDim.x + threadIdx.x;
    if (i >= 4 * 16 * 128 * 4) return;
    int c16 = i & 3;
    int r   = (i >> 2) & 127;
    int kt  = (i >> 9) & 15;
    int p   = i >> 13;
    int usrc = c16 ^ ((r >> 1) & 3);
    int kbase = kt * 16 + usrc * 4;
    float4 w = *(const float4*)&W1[(long long)(p * 128 + r) * NI + kbase];
    float f[4] = {w.x, w.y, w.z, w.w};
    uint4 o;
    unsigned int* op = &o.x;
    #pragma unroll
    for (int j = 0; j < 4; ++j) {
        unsigned int hb = __float_as_uint(f[j]) >> 16;   // exact for 0 / 0.5
        op[j] = hb | (hb << 16);
    }
    ((uint4*)Wimg)[i] = o;
}

// ---- GEMM1: R2 structure + counted-vmcnt barrier (T4) ----
__launch_bounds__(256, 2)
__global__ void gemm1_kernel(const float* __restrict__ x, const short* __restrict__ Wimg,
                             float* __restrict__ C) {
    __shared__ short As[2][128][40];
    __shared__ short Ws[2][128][32];
    const int tid = threadIdx.x;
    const int bid = blockIdx.x;
    const int x8 = bid & 7;
    const int g  = bid >> 3;
    const int p  = g & 3;
    const int panel = (g >> 2) * 8 + x8;
    const int m0 = (799 - panel) * 128;    // reversed: high t written first
    const int n0 = p * 128;
    const int wid = tid >> 6;
    const int lane = tid & 63;
    const int wm = (wid >> 1) * 64;
    const int wn = (wid & 1) * 64;

    f32x4 acc[4][4] = {};

    const int srow = tid >> 2;
    const int sc4 = tid & 3;
    const long long ax0 = (long long)(m0 + srow) * NI + sc4 * 4;
    const long long ax1 = ax0 + 64LL * NI;

    const int fr = lane & 15;
    const int fk = (lane >> 4) * 8;
    const int swz = (((lane >> 4) ^ ((fr >> 1) & 3)) << 4);

    const short* wbase = Wimg + (long long)p * 16 * 4096;
    const int c0 = wid * 2;

    gload16(wbase + (c0    ) * 512 + lane * 8, (char*)&Ws[0][0][0] + (c0    ) * 1024);
    gload16(wbase + (c0 + 1) * 512 + lane * 8, (char*)&Ws[0][0][0] + (c0 + 1) * 1024);
    uint4 pa0, pa1;
    {
        float4 t0a = *(const float4*)&x[ax0];
        float4 t0b = *(const float4*)&x[ax1];
        uint4 q0, q1;
        pack4(q0, t0a); pack4(q1, t0b);
        *(uint4*)&As[0][srow][sc4 * 8]      = q0;
        *(uint4*)&As[0][srow + 64][sc4 * 8] = q1;
        float4 t1a = *(const float4*)&x[ax0 + 16];
        float4 t1b = *(const float4*)&x[ax1 + 16];
        pack4(pa0, t1a); pack4(pa1, t1b);
    }
    float4 raw0a = *(const float4*)&x[ax0 + 32];
    float4 raw0b = *(const float4*)&x[ax1 + 32];
    float4 raw1a = *(const float4*)&x[ax0 + 48];
    float4 raw1b = *(const float4*)&x[ax1 + 48];
    __syncthreads();   // prologue: full drain (one-time)

    #pragma unroll
    for (int kt = 0; kt < 16; ++kt) {
        const int cur = kt & 1;
        const int nxt = cur ^ 1;

        // --- phase 1: issue W gloads (oldest VMEM this iter) + As ds_write ---
        if (kt + 1 < 16) {
            const short* wt = wbase + (kt + 1) * 4096;
            gload16(wt + (c0    ) * 512 + lane * 8, (char*)&Ws[nxt][0][0] + (c0    ) * 1024);
            gload16(wt + (c0 + 1) * 512 + lane * 8, (char*)&Ws[nxt][0][0] + (c0 + 1) * 1024);
            *(uint4*)&As[nxt][srow][sc4 * 8]      = pa0;
            *(uint4*)&As[nxt][srow + 64][sc4 * 8] = pa1;
        }
        // pin: raw loads below must not be hoisted above the gloads
        __builtin_amdgcn_sched_barrier(0);

        // --- phase 2: pack kt+2 from regs; issue raw loads (newest VMEM) ---
        if (kt + 2 < 16) {
            if (cur == 0) { pack4(pa0, raw0a); pack4(pa1, raw0b); }
            else          { pack4(pa0, raw1a); pack4(pa1, raw1b); }
        }
        if (kt < 15) {
            // clamped on tail iters (dummy, never packed) to keep the per-iter
            // VMEM pattern [gload x2, raw x2] invariant for vmcnt(2)
            const int ktn = (kt + 4 < 16) ? kt + 4 : 15;
            if (cur == 0) {
                raw0a = *(const float4*)&x[ax0 + (long long)ktn * 16];
                raw0b = *(const float4*)&x[ax1 + (long long)ktn * 16];
            } else {
                raw1a = *(const float4*)&x[ax0 + (long long)ktn * 16];
                raw1b = *(const float4*)&x[ax1 + (long long)ktn * 16];
            }
        }

        // --- phase 3: fragments + MFMA ---
        bf16x8 af[4], wf[4];
        #pragma unroll
        for (int i = 0; i < 4; ++i) {
            af[i] = *(const bf16x8*)&As[cur][wm + i * 16 + fr][fk];
            wf[i] = *(const bf16x8*)((const char*)&Ws[cur][wn + i * 16 + fr][0] + swz);
        }
        #pragma unroll
        for (int i = 0; i < 4; ++i)
            #pragma unroll
            for (int j = 0; j < 4; ++j)
                acc[i][j] = __builtin_amdgcn_mfma_f32_16x16x32_bf16(af[i], wf[j], acc[i][j], 0, 0, 0);

        // --- phase 4: counted barrier (drains gloads, keeps raws in flight) ---
        if (kt + 1 < 16) barrier_vm2();
    }

    const int col = lane & 15;
    const int rbase = (lane >> 4) * 4;
    #pragma unroll
    for (int i = 0; i < 4; ++i) {
        #pragma unroll
        for (int j = 0; j < 4; ++j) {
            long long base = (long long)(m0 + wm + i * 16 + rbase) * GN + (n0 + wn + j * 16 + col);
            #pragma unroll
            for (int r = 0; r < 4; ++r)
                C[base + (long long)r * GN] = acc[i][j][r];
        }
    }
}

// ---- fused LIF1 + GEMM2(popcount) + LIF2 (R7-proven) ----
__launch_bounds__(512)
__global__ void lif_kernel(const float* __restrict__ cur1, const float* __restrict__ W2,
                           float* __restrict__ out) {
    const int b = blockIdx.x;       // 0..1023
    const int h = threadIdx.x;      // 0..511
    const int w = h >> 6;
    const int lane = h & 63;

    __shared__ unsigned long long wmks[2][2][8];   // [iter parity][t parity][wave]
    __shared__ unsigned long long w2ms[NO][8];

    #pragma unroll
    for (int o = 0; o < NO; ++o) {
        unsigned long long mk = __ballot(W2[o * NH + h] != 0.0f);
        if (lane == 0) w2ms[o][w] = mk;
    }
    __syncthreads();
    unsigned long long w2m[8];
    if (h < NO) {
        #pragma unroll
        for (int i = 0; i < 8; ++i) w2m[i] = w2ms[h][i];
    }

    float m1 = 0.0f, m2 = 0.0f;
    const long long idx1 = (long long)b * NH + h;
    const float* c1p = cur1 + idx1;
    float* s1p = out + S1_OFF + idx1;
    float* m1p = out + M1_OFF + idx1;
    const long long st1 = (long long)BB * NH;   // per-t stride

    float c1a = c1p[0];
    float c1b = c1p[st1];
    for (int t = 0; t < TT; t += 2) {
        const int par = (t >> 1) & 1;

        float c1c = 0.0f, c1d = 0.0f;
        if (t + 2 < TT) c1c = c1p[(long long)(t + 2) * st1];
        if (t + 3 < TT) c1d = c1p[(long long)(t + 3) * st1];

        float rst = (m1 > 1.0f) ? 1.0f : 0.0f;
        m1 = 0.9f * m1 + c1a - rst;
        float s1a = (m1 > 1.0f) ? 1.0f : 0.0f;
        s1p[(long long)t * st1] = s1a;
        m1p[(long long)t * st1] = m1;
        unsigned long long mka = __ballot(s1a != 0.0f);
        if (lane == 0) wmks[par][0][w] = mka;

        float rstb = (m1 > 1.0f) ? 1.0f : 0.0f;
        m1 = 0.9f * m1 + c1b - rstb;
        float s1b = (m1 > 1.0f) ? 1.0f : 0.0f;
        s1p[(long long)(t + 1) * st1] = s1b;
        m1p[(long long)(t + 1) * st1] = m1;
        unsigned long long mkb = __ballot(s1b != 0.0f);
        if (lane == 0) wmks[par][1][w] = mkb;

        barrier_lds();   // orders the wmks ds_writes only; stores stay in flight

        if (h < NO) {
            #pragma unroll
            for (int j = 0; j < 2; ++j) {
                int cnt = 0;
                #pragma unroll
                for (int i = 0; i < 8; ++i) cnt += __popcll(wmks[par][j][i] & w2m[i]);
                float c2 = 0.5f * (float)cnt;    // exact: multiples of 0.5
                float rst2 = (m2 > 1.0f) ? 1.0f : 0.0f;
                m2 = 0.8f * m2 + c2 - rst2;
                float s2 = (m2 > 1.0f) ? 1.0f : 0.0f;
                long long o2 = (long long)(t + j) * (BB * NO) + b * NO + h;
                out[C2_OFF + o2] = c2;
                out[S2_OFF + o2] = s2;
                out[M2_OFF + o2] = m2;
            }
        }
        c1a = c1c; c1b = c1d;
        // no trailing barrier: wmks double-buffered by iteration parity
    }
}

extern "C" void kernel_launch(void* const* d_in, const int* in_sizes, int n_in,
                              void* d_out, int out_size, void* d_ws, size_t ws_size,
                              hipStream_t stream) {
    const float* x  = (const float*)d_in[0];
    const float* W1 = (const float*)d_in[1];
    const float* W2 = (const float*)d_in[2];
    float* out = (float*)d_out;

    // scratch inside d_out: W image (512KB bf16) at start of spk1 region;
    // consumed by gemm1 before lif_kernel overwrites it (stream-ordered).
    short* Wp = (short*)(out + S1_OFF);
    float* C1 = out + C1_OFF;

    {
        int units = NH * GK / 8;   // 32,768 16B-units
        prep_w_kernel<<<(units + 255) / 256, 256, 0, stream>>>(W1, Wp);
    }
    gemm1_kernel<<<(TB / 128) * (GN / 128), 256, 0, stream>>>(x, Wp, C1);
    lif_kernel<<<BB, NH, 0, stream>>>(C1, W2, out);
}

// Round 9
// 260.984 us; speedup vs baseline: 1.0846x; 1.0846x over previous
//
#include <hip/hip_runtime.h>

// ---- problem constants ----
#define TT 100
#define BB 1024
#define NI 256
#define NH 512
#define NO 10
#define TB (TT*BB)            // 102400 rows
#define GK 512                 // doubled K (hi/lo interleave)
#define GN 512

// output layout (floats), return order: cur1, cur2, spk1, spk2, mem1, mem2
constexpr long long C1_OFF = 0;
constexpr long long C2_OFF = 52428800LL;            // + T*B*NH
constexpr long long S1_OFF = 53452800LL;            // + T*B*NO
constexpr long long S2_OFF = 105881600LL;
constexpr long long M1_OFF = 106905600LL;
constexpr long long M2_OFF = 159334400LL;

typedef short bf16x8 __attribute__((ext_vector_type(8)));
typedef float f32x4 __attribute__((ext_vector_type(4)));

// round-to-nearest-even f32 -> bf16 bits
__device__ __forceinline__ unsigned int rne_bf16(float f) {
    unsigned int u = __float_as_uint(f);
    return (u + 0x7fffu + ((u >> 16) & 1u)) >> 16;
}

// f32 -> packed [hi,lo] bf16 pair (Dekker split), bit-identical to prior rounds
__device__ __forceinline__ unsigned int pack_hilo(float f) {
    unsigned int hi = rne_bf16(f);
    float hif = __uint_as_float(hi << 16);
    float e = f - hif;
    unsigned int lo = rne_bf16(e);
    return (hi & 0xffffu) | (lo << 16);
}

__device__ __forceinline__ void pack4(uint4& d, const float4& a) {
    d.x = pack_hilo(a.x); d.y = pack_hilo(a.y); d.z = pack_hilo(a.z); d.w = pack_hilo(a.w);
}

// async global->LDS, 16B per lane; LDS dest = wave-uniform base + lane*16
__device__ __forceinline__ void gload16(const void* g, void* l) {
    __builtin_amdgcn_global_load_lds(
        (const __attribute__((address_space(1))) void*)g,
        (__attribute__((address_space(3))) void*)l, 16, 0, 0);
}

// LDS-only barrier (R5-proven correct): orders ds traffic without draining the
// global store stream (__syncthreads would emit s_waitcnt vmcnt(0)).
__device__ __forceinline__ void barrier_lds() {
    asm volatile("s_waitcnt lgkmcnt(0)" ::: "memory");
    __builtin_amdgcn_s_barrier();
}

// ---- prep: W1 (f32 {0,0.5}) -> pre-swizzled LDS-image (R2-proven) ----
__global__ void prep_w_kernel(const float* __restrict__ W1, short* __restrict__ Wimg) {
    int i = blockIdx.x * blockDim.x + threadIdx.x;
    if (i >= 4 * 16 * 128 * 4) return;
    int c16 = i & 3;
    int r   = (i >> 2) & 127;
    int kt  = (i >> 9) & 15;
    int p   = i >> 13;
    int usrc = c16 ^ ((r >> 1) & 3);
    int kbase = kt * 16 + usrc * 4;
    float4 w = *(const float4*)&W1[(long long)(p * 128 + r) * NI + kbase];
    float f[4] = {w.x, w.y, w.z, w.w};
    uint4 o;
    unsigned int* op = &o.x;
    #pragma unroll
    for (int j = 0; j < 4; ++j) {
        unsigned int hb = __float_as_uint(f[j]) >> 16;   // exact for 0 / 0.5
        op[j] = hb | (hb << 16);
    }
    ((uint4*)Wimg)[i] = o;
}

// ---- GEMM1 (R2/R7 structure; ONLY change: occupancy 2 -> 3 blocks/CU) ----
// launch_bounds(256,3): VGPR cap ~170 (persistent regs ~88, spill-free),
// LDS 3x36KB = 108KB <= 160KB. 12 waves/CU to cover barrier/load stalls.
__launch_bounds__(256, 3)
__global__ void gemm1_kernel(const float* __restrict__ x, const short* __restrict__ Wimg,
                             float* __restrict__ C) {
    __shared__ short As[2][128][40];
    __shared__ short Ws[2][128][32];
    const int tid = threadIdx.x;
    const int bid = blockIdx.x;
    const int x8 = bid & 7;
    const int g  = bid >> 3;
    const int p  = g & 3;
    const int panel = (g >> 2) * 8 + x8;
    const int m0 = (799 - panel) * 128;    // reversed: high t written first
    const int n0 = p * 128;
    const int wid = tid >> 6;
    const int lane = tid & 63;
    const int wm = (wid >> 1) * 64;
    const int wn = (wid & 1) * 64;

    f32x4 acc[4][4] = {};

    const int srow = tid >> 2;
    const int sc4 = tid & 3;
    const long long ax0 = (long long)(m0 + srow) * NI + sc4 * 4;
    const long long ax1 = ax0 + 64LL * NI;

    const int fr = lane & 15;
    const int fk = (lane >> 4) * 8;
    const int swz = (((lane >> 4) ^ ((fr >> 1) & 3)) << 4);

    const short* wbase = Wimg + (long long)p * 16 * 4096;
    const int c0 = wid * 2;

    gload16(wbase + (c0    ) * 512 + lane * 8, (char*)&Ws[0][0][0] + (c0    ) * 1024);
    gload16(wbase + (c0 + 1) * 512 + lane * 8, (char*)&Ws[0][0][0] + (c0 + 1) * 1024);
    uint4 pa0, pa1;
    {
        float4 t0a = *(const float4*)&x[ax0];
        float4 t0b = *(const float4*)&x[ax1];
        uint4 q0, q1;
        pack4(q0, t0a); pack4(q1, t0b);
        *(uint4*)&As[0][srow][sc4 * 8]      = q0;
        *(uint4*)&As[0][srow + 64][sc4 * 8] = q1;
        float4 t1a = *(const float4*)&x[ax0 + 16];
        float4 t1b = *(const float4*)&x[ax1 + 16];
        pack4(pa0, t1a); pack4(pa1, t1b);
    }
    float4 raw0a = *(const float4*)&x[ax0 + 32];
    float4 raw0b = *(const float4*)&x[ax1 + 32];
    float4 raw1a = *(const float4*)&x[ax0 + 48];
    float4 raw1b = *(const float4*)&x[ax1 + 48];
    __syncthreads();

    #pragma unroll
    for (int kt = 0; kt < 16; ++kt) {
        const int cur = kt & 1;
        const int nxt = cur ^ 1;

        if (kt + 1 < 16) {
            const short* wt = wbase + (kt + 1) * 4096;
            gload16(wt + (c0    ) * 512 + lane * 8, (char*)&Ws[nxt][0][0] + (c0    ) * 1024);
            gload16(wt + (c0 + 1) * 512 + lane * 8, (char*)&Ws[nxt][0][0] + (c0 + 1) * 1024);
            *(uint4*)&As[nxt][srow][sc4 * 8]      = pa0;
            *(uint4*)&As[nxt][srow + 64][sc4 * 8] = pa1;
        }
        if (kt + 2 < 16) {
            if (cur == 0) { pack4(pa0, raw0a); pack4(pa1, raw0b); }
            else          { pack4(pa0, raw1a); pack4(pa1, raw1b); }
        }
        if (kt + 4 < 16) {
            if (cur == 0) {
                raw0a = *(const float4*)&x[ax0 + (long long)(kt + 4) * 16];
                raw0b = *(const float4*)&x[ax1 + (long long)(kt + 4) * 16];
            } else {
                raw1a = *(const float4*)&x[ax0 + (long long)(kt + 4) * 16];
                raw1b = *(const float4*)&x[ax1 + (long long)(kt + 4) * 16];
            }
        }

        bf16x8 af[4], wf[4];
        #pragma unroll
        for (int i = 0; i < 4; ++i) {
            af[i] = *(const bf16x8*)&As[cur][wm + i * 16 + fr][fk];
            wf[i] = *(const bf16x8*)((const char*)&Ws[cur][wn + i * 16 + fr][0] + swz);
        }
        #pragma unroll
        for (int i = 0; i < 4; ++i)
            #pragma unroll
            for (int j = 0; j < 4; ++j)
                acc[i][j] = __builtin_amdgcn_mfma_f32_16x16x32_bf16(af[i], wf[j], acc[i][j], 0, 0, 0);

        if (kt + 1 < 16) __syncthreads();
    }

    const int col = lane & 15;
    const int rbase = (lane >> 4) * 4;
    #pragma unroll
    for (int i = 0; i < 4; ++i) {
        #pragma unroll
        for (int j = 0; j < 4; ++j) {
            long long base = (long long)(m0 + wm + i * 16 + rbase) * GN + (n0 + wn + j * 16 + col);
            #pragma unroll
            for (int r = 0; r < 4; ++r)
                C[base + (long long)r * GN] = acc[i][j][r];
        }
    }
}

// ---- fused LIF1 + GEMM2(popcount) + LIF2 (R7-proven, unchanged) ----
__launch_bounds__(512)
__global__ void lif_kernel(const float* __restrict__ cur1, const float* __restrict__ W2,
                           float* __restrict__ out) {
    const int b = blockIdx.x;       // 0..1023
    const int h = threadIdx.x;      // 0..511
    const int w = h >> 6;
    const int lane = h & 63;

    __shared__ unsigned long long wmks[2][2][8];   // [iter parity][t parity][wave]
    __shared__ unsigned long long w2ms[NO][8];

    #pragma unroll
    for (int o = 0; o < NO; ++o) {
        unsigned long long mk = __ballot(W2[o * NH + h] != 0.0f);
        if (lane == 0) w2ms[o][w] = mk;
    }
    __syncthreads();
    unsigned long long w2m[8];
    if (h < NO) {
        #pragma unroll
        for (int i = 0; i < 8; ++i) w2m[i] = w2ms[h][i];
    }

    float m1 = 0.0f, m2 = 0.0f;
    const long long idx1 = (long long)b * NH + h;
    const float* c1p = cur1 + idx1;
    float* s1p = out + S1_OFF + idx1;
    float* m1p = out + M1_OFF + idx1;
    const long long st1 = (long long)BB * NH;   // per-t stride

    float c1a = c1p[0];
    float c1b = c1p[st1];
    for (int t = 0; t < TT; t += 2) {
        const int par = (t >> 1) & 1;

        float c1c = 0.0f, c1d = 0.0f;
        if (t + 2 < TT) c1c = c1p[(long long)(t + 2) * st1];
        if (t + 3 < TT) c1d = c1p[(long long)(t + 3) * st1];

        float rst = (m1 > 1.0f) ? 1.0f : 0.0f;
        m1 = 0.9f * m1 + c1a - rst;
        float s1a = (m1 > 1.0f) ? 1.0f : 0.0f;
        s1p[(long long)t * st1] = s1a;
        m1p[(long long)t * st1] = m1;
        unsigned long long mka = __ballot(s1a != 0.0f);
        if (lane == 0) wmks[par][0][w] = mka;

        float rstb = (m1 > 1.0f) ? 1.0f : 0.0f;
        m1 = 0.9f * m1 + c1b - rstb;
        float s1b = (m1 > 1.0f) ? 1.0f : 0.0f;
        s1p[(long long)(t + 1) * st1] = s1b;
        m1p[(long long)(t + 1) * st1] = m1;
        unsigned long long mkb = __ballot(s1b != 0.0f);
        if (lane == 0) wmks[par][1][w] = mkb;

        barrier_lds();   // orders the wmks ds_writes only; stores stay in flight

        if (h < NO) {
            #pragma unroll
            for (int j = 0; j < 2; ++j) {
                int cnt = 0;
                #pragma unroll
                for (int i = 0; i < 8; ++i) cnt += __popcll(wmks[par][j][i] & w2m[i]);
                float c2 = 0.5f * (float)cnt;    // exact: multiples of 0.5
                float rst2 = (m2 > 1.0f) ? 1.0f : 0.0f;
                m2 = 0.8f * m2 + c2 - rst2;
                float s2 = (m2 > 1.0f) ? 1.0f : 0.0f;
                long long o2 = (long long)(t + j) * (BB * NO) + b * NO + h;
                out[C2_OFF + o2] = c2;
                out[S2_OFF + o2] = s2;
                out[M2_OFF + o2] = m2;
            }
        }
        c1a = c1c; c1b = c1d;
        // no trailing barrier: wmks double-buffered by iteration parity
    }
}

extern "C" void kernel_launch(void* const* d_in, const int* in_sizes, int n_in,
                              void* d_out, int out_size, void* d_ws, size_t ws_size,
                              hipStream_t stream) {
    const float* x  = (const float*)d_in[0];
    const float* W1 = (const float*)d_in[1];
    const float* W2 = (const float*)d_in[2];
    float* out = (float*)d_out;

    // scratch inside d_out: W image (512KB bf16) at start of spk1 region;
    // consumed by gemm1 before lif_kernel overwrites it (stream-ordered).
    short* Wp = (short*)(out + S1_OFF);
    float* C1 = out + C1_OFF;

    {
        int units = NH * GK / 8;   // 32,768 16B-units
        prep_w_kernel<<<(units + 255) / 256, 256, 0, stream>>>(W1, Wp);
    }
    gemm1_kernel<<<(TB / 128) * (GN / 128), 256, 0, stream>>>(x, Wp, C1);
    lif_kernel<<<BB, NH, 0, stream>>>(C1, W2, out);
}